// Round 14
// baseline (817.225 us; speedup 1.0000x reference)
//
#include <hip/hip_runtime.h>
#include <math.h>

#define Bq    1024
#define Nn    29
#define DIMq  64
#define Kq    8
#define MD    16
#define EIN   129
#define EH    258   // 2*EIN
#define CHID  64    // 4*MD
#define NIN   80    // DIM+MD
#define NHID  128   // 2*DIM
#define DEPTHq 4
#define NPASS 4
#define PQS   68    // P/Q LDS row stride (64+4)
#define FS    68    // s_f row stride
#define UPQN  6032  // max(2*29*68=3944, ni 2320 + nh 3712 = 6032)

typedef __attribute__((ext_vector_type(2))) float f32x2;

__device__ __forceinline__ f32x2 fma2(f32x2 a, f32x2 b, f32x2 c) {
    return __builtin_elementwise_fma(a, b, c);
}
__device__ __forceinline__ f32x2 bc2(float x) { f32x2 r; r.x = x; r.y = x; return r; }

__device__ __forceinline__ float silu_f(float x) {
    float e = __expf(-x);
    return x * __builtin_amdgcn_rcpf(1.0f + e);
}

// R8 structure VERBATIM (616us known-good: 4-pass P/Q, full-width node MLP in
// LDS, launch_bounds(256,4) — (512,8)/(256,5) spill catastrophically, R6/R11)
// + ONE delta: packed v_pk_fma_f32 on the two phases whose weights are
// WAVE-UNIFORM (edge m-update: ew2[c][:] via SGPR pairs; coor-MLP hh-update:
// cw1 via SGPR pairs). Task shapes, LDS layout, and all memory patterns are
// byte-identical to R8 (R10's regression was reshaped tasks, not pk itself).
// Per-element accumulation order unchanged -> bit-identical output.
__global__ __launch_bounds__(256, 4)
void k_egnn(const int* __restrict__ tokens, const float* __restrict__ coords,
            const float* __restrict__ temb, const float* __restrict__ pemb,
            const float* __restrict__ ew1, const float* __restrict__ eb1,
            const float* __restrict__ ew2, const float* __restrict__ eb2,
            const float* __restrict__ cw1, const float* __restrict__ cb1,
            const float* __restrict__ cw2, const float* __restrict__ cb2,
            const float* __restrict__ csc,
            const float* __restrict__ lng, const float* __restrict__ lnb,
            const float* __restrict__ nw1, const float* __restrict__ nb1,
            const float* __restrict__ nw2, const float* __restrict__ nb2,
            const float* __restrict__ rw1, const float* __restrict__ rb1,
            const float* __restrict__ rw2, const float* __restrict__ rb2,
            float* __restrict__ out) {
    __shared__ float uPQ[UPQN];            // P/Q panels per pass; later ni/nh; finally mol
    __shared__ float s_f[Nn][FS];          // persistent feats
    __shared__ float s_c[2][Nn][3];        // coords double-buffered
    __shared__ int   s_idx[Nn][Kq];
    __shared__ float s_dk[Nn][Kq];
    __shared__ union RegB {                // d2 dead after kNN -> cw/mi
        float d2[Nn][Nn];
        struct { float cw[232]; float mi[Nn][MD]; } e;
    } ub;
    float* s_ni = uPQ;                     // [Nn][NIN]
    float* s_nh = uPQ + Nn * NIN;          // [Nn][NHID]

    const int b = blockIdx.x;
    const int tid = threadIdx.x;

    // ---- init: feats = token_emb + pos_emb ; stage coords ----
    for (int o = tid; o < Nn * DIMq; o += 256) {
        int n = o >> 6, d = o & 63;
        s_f[n][d] = temb[tokens[b * Nn + n] * DIMq + d] + pemb[o];
    }
    if (tid < Nn * 3) s_c[0][0][tid] = coords[(size_t)b * Nn * 3 + tid];
    int cp = 0;

    for (int l = 0; l < DEPTHq; ++l) {
        const float* ew1l = ew1 + (size_t)l * EIN * EH;  const float* eb1l = eb1 + l * EH;
        const float* ew2l = ew2 + (size_t)l * EH * MD;   const float* eb2l = eb2 + l * MD;
        const float* cw1l = cw1 + (size_t)l * MD * CHID; const float* cb1l = cb1 + l * CHID;
        const float* cw2l = cw2 + l * CHID;              const float* cb2l = cb2 + l;
        const float* lngl = lng + l * DIMq;              const float* lnbl = lnb + l * DIMq;
        const float* nw1l = nw1 + (size_t)l * NIN * NHID;  const float* nb1l = nb1 + l * NHID;
        const float* nw2l = nw2 + (size_t)l * NHID * DIMq; const float* nb2l = nb2 + l * DIMq;
        const float cscale = csc[l];

        __syncthreads();   // s_f/s_c/uPQ stable before this layer reads them

        // ---- all-pairs squared distances (exact rounding: kNN-critical) ----
        for (int o = tid; o < Nn * Nn; o += 256) {
            int i = o / Nn, j = o % Nn;
            float dx = __fsub_rn(s_c[cp][i][0], s_c[cp][j][0]);
            float dy = __fsub_rn(s_c[cp][i][1], s_c[cp][j][1]);
            float dz = __fsub_rn(s_c[cp][i][2], s_c[cp][j][2]);
            ub.d2[i][j] = __fadd_rn(__fadd_rn(__fmul_rn(dx, dx), __fmul_rn(dy, dy)),
                                    __fmul_rn(dz, dz));
        }
        __syncthreads();

        // ---- parallel stable K-nearest: 8 lanes per node (tie: dist2, then index) ----
        if (tid < Nn * Kq) {
            const int g = tid >> 3, lk = tid & 7;
            unsigned chosen = 0;
            for (int r = 0; r < Kq; ++r) {
                float bv = 3.4e38f; int bj = 64;
                for (int j = lk; j < Nn; j += 8) {
                    if ((chosen >> j) & 1u) continue;
                    float v = ub.d2[g][j];
                    if (v < bv) { bv = v; bj = j; }
                }
                #pragma unroll
                for (int off = 1; off < 8; off <<= 1) {
                    float ov = __shfl_xor(bv, off);
                    int   oj = __shfl_xor(bj, off);
                    if (ov < bv || (ov == bv && oj < bj)) { bv = ov; bj = oj; }
                }
                chosen |= 1u << bj;
                if (lk == 0) { s_idx[g][r] = bj; s_dk[g][r] = bv; }
            }
        }
        __syncthreads();

        // ---- edge state (uniform flow; writes masked) ----
        const int e   = (tid < 232) ? tid : 231;
        const int n_e = e >> 3;
        const int k_e = e & 7;
        const int jj  = s_idx[n_e][k_e];
        const float dd = s_dk[n_e][k_e];
        f32x2 m2[8];                        // packed m accumulator (pairs of MD cols)
        #pragma unroll
        for (int q = 0; q < 8; ++q) m2[q] = bc2(0.f);

// packed m-update: weights uniform -> SGPR pairs; h splat -> v_pk_fma_f32
#define ACC_COL(Pv, Qv, CG) do {                                   \
        float pre = (Pv) + (Qv) + dd * wdrow[CG];                  \
        f32x2 h2 = bc2(silu_f(pre));                               \
        const f32x2* w2p = (const f32x2*)(ew2l + (size_t)(CG) * MD);\
        _Pragma("unroll")                                          \
        for (int qp = 0; qp < 8; ++qp) m2[qp] = fma2(h2, w2p[qp], m2[qp]);\
    } while (0)

        // ---- four c-passes (64,64,64,66 cols): P/Q panels -> edge accumulation ----
        for (int pass = 0; pass < NPASS; ++pass) {
            const int c0 = pass * 64;
            const int cols = (pass == 3) ? 66 : 64;

            // P/Q: 4*cols tasks = cols x {P,Q} x {rows 0-14, 15-28}; 256 tasks/pass
            for (int it = 0; it < 2; ++it) {
                const int t = tid + it * 256;
                if (t >= 4 * cols) break;
                const int cl = t >> 2, r = t & 3;
                const bool isP = r < 2;
                const bool full15 = (r & 1) == 0;
                const int n0 = (r & 1) * 15;
                const int cg = c0 + cl;
                const float* wcol = ew1l + (isP ? 0 : 64) * EH + cg;
                float init = isP ? eb1l[cg] : 0.f;
                float acc[15];
                #pragma unroll
                for (int u = 0; u < 15; ++u) acc[u] = init;
                #pragma unroll 2
                for (int ig = 0; ig < 16; ++ig) {
                    float w0 = wcol[(4 * ig + 0) * EH], w1 = wcol[(4 * ig + 1) * EH];
                    float w2v = wcol[(4 * ig + 2) * EH], w3 = wcol[(4 * ig + 3) * EH];
                    #pragma unroll
                    for (int u = 0; u < 14; ++u) {
                        float4 f4 = *(const float4*)&s_f[n0 + u][4 * ig];
                        acc[u] = fmaf(f4.x, w0, acc[u]);
                        acc[u] = fmaf(f4.y, w1, acc[u]);
                        acc[u] = fmaf(f4.z, w2v, acc[u]);
                        acc[u] = fmaf(f4.w, w3, acc[u]);
                    }
                    if (full15) {
                        float4 f4 = *(const float4*)&s_f[14][4 * ig];
                        acc[14] = fmaf(f4.x, w0, acc[14]);
                        acc[14] = fmaf(f4.y, w1, acc[14]);
                        acc[14] = fmaf(f4.z, w2v, acc[14]);
                        acc[14] = fmaf(f4.w, w3, acc[14]);
                    }
                }
                const int rbase = (isP ? 0 : Nn) + n0;
                #pragma unroll
                for (int u = 0; u < 14; ++u) uPQ[(rbase + u) * PQS + cl] = acc[u];
                if (full15) uPQ[(rbase + 14) * PQS + cl] = acc[14];
            }
            __syncthreads();

            // edge accumulation over this pass (uniform loop; packed m-update)
            {
                const float* Prow = uPQ + n_e * PQS;
                const float* Qrow = uPQ + (Nn + jj) * PQS;
                const float* wdrow = ew1l + 128 * EH;
                for (int qd = 0; qd < 16; ++qd) {
                    const int cl = 4 * qd;
                    float4 P4 = *(const float4*)(Prow + cl);
                    float4 Q4 = *(const float4*)(Qrow + cl);
                    const int cg = c0 + cl;
                    ACC_COL(P4.x, Q4.x, cg);
                    ACC_COL(P4.y, Q4.y, cg + 1);
                    ACC_COL(P4.z, Q4.z, cg + 2);
                    ACC_COL(P4.w, Q4.w, cg + 3);
                }
                if (pass == 3) {
                    ACC_COL(Prow[64], Qrow[64], c0 + 64);
                    ACC_COL(Prow[65], Qrow[65], c0 + 65);
                }
            }
            __syncthreads();
        }
#undef ACC_COL

        // ---- finish edge: m silu, coor MLP (packed), cw + mi pool ----
        {
            float m[MD];
            #pragma unroll
            for (int qp = 0; qp < 8; ++qp) { m[2 * qp] = m2[qp].x; m[2 * qp + 1] = m2[qp].y; }
            #pragma unroll
            for (int q = 0; q < MD; ++q) m[q] = silu_f(eb2l[q] + m[q]);

            float cwacc = cb2l[0];
            #pragma unroll
            for (int ch = 0; ch < 4; ++ch) {
                f32x2 hh2[8];
                const f32x2* cb1c = (const f32x2*)(cb1l + 16 * ch);
                #pragma unroll
                for (int p = 0; p < 8; ++p) hh2[p] = cb1c[p];
                #pragma unroll
                for (int i = 0; i < MD; ++i) {
                    f32x2 mi2 = bc2(m[i]);
                    const f32x2* wr = (const f32x2*)(cw1l + i * CHID + 16 * ch); // uniform
                    #pragma unroll
                    for (int p = 0; p < 8; ++p) hh2[p] = fma2(mi2, wr[p], hh2[p]);
                }
                const float* cw2c = cw2l + 16 * ch;
                #pragma unroll
                for (int p = 0; p < 8; ++p) {
                    cwacc = fmaf(silu_f(hh2[p].x), cw2c[2 * p], cwacc);
                    cwacc = fmaf(silu_f(hh2[p].y), cw2c[2 * p + 1], cwacc);
                }
            }
            cwacc = fminf(fmaxf(cwacc, -2.f), 2.f);
            if (tid < 232) ub.e.cw[e] = cwacc;

            #pragma unroll
            for (int q = 0; q < MD; ++q) {
                float v = m[q];
                v += __shfl_xor(v, 1);
                v += __shfl_xor(v, 2);
                v += __shfl_xor(v, 4);
                if (k_e == 0 && tid < 232) ub.e.mi[n_e][q] = v;
            }
        }
        __syncthreads();

        // ---- coords update (87 lanes -> s_c[cp^1]) + LayerNorm/ni build (232 lanes) ----
        if (tid < Nn * 3) {
            int n2 = tid / 3, cix = tid % 3;
            float acc2 = 0.f;
            for (int k2 = 0; k2 < Kq; ++k2) {
                int j2 = s_idx[n2][k2];
                float nrm = sqrtf(s_dk[n2][k2]);
                float rel = __fsub_rn(s_c[cp][n2][cix], s_c[cp][j2][cix]);
                float rn = rel / fmaxf(nrm, 1e-8f) * cscale;
                acc2 = fmaf(ub.e.cw[n2 * Kq + k2], rn, acc2);
            }
            s_c[cp ^ 1][n2][cix] = s_c[cp][n2][cix] + acc2;   // write other buffer: no race
        }
        if (tid < Nn * Kq) {
            const int g = tid >> 3, lk = tid & 7;
            const float* fr = s_f[g];
            float4 a = *(const float4*)&fr[8 * lk];
            float4 b4 = *(const float4*)&fr[8 * lk + 4];
            float ps = ((a.x + a.y) + (a.z + a.w)) + ((b4.x + b4.y) + (b4.z + b4.w));
            ps += __shfl_xor(ps, 1); ps += __shfl_xor(ps, 2); ps += __shfl_xor(ps, 4);
            float mu = ps * (1.0f / 64.0f);
            float t0, pv = 0.f;
            t0 = a.x - mu;  pv = fmaf(t0, t0, pv);  t0 = a.y - mu;  pv = fmaf(t0, t0, pv);
            t0 = a.z - mu;  pv = fmaf(t0, t0, pv);  t0 = a.w - mu;  pv = fmaf(t0, t0, pv);
            t0 = b4.x - mu; pv = fmaf(t0, t0, pv);  t0 = b4.y - mu; pv = fmaf(t0, t0, pv);
            t0 = b4.z - mu; pv = fmaf(t0, t0, pv);  t0 = b4.w - mu; pv = fmaf(t0, t0, pv);
            pv += __shfl_xor(pv, 1); pv += __shfl_xor(pv, 2); pv += __shfl_xor(pv, 4);
            float rs = rsqrtf(pv * (1.0f / 64.0f) + 1e-5f);
            #pragma unroll
            for (int u = 0; u < 8; ++u) {
                int d = 8 * lk + u;
                s_ni[g * NIN + d] = (fr[d] - mu) * rs * lngl[d] + lnbl[d];
            }
            if (lk < 2) {
                #pragma unroll
                for (int u = 0; u < 8; ++u)
                    s_ni[g * NIN + DIMq + 8 * lk + u] = ub.e.mi[g][8 * lk + u];
            }
        }
        __syncthreads();

        // ---- node MLP hidden (full 128-wide, LDS-resident; scalar — per-lane weights) ----
        for (int o = tid; o < Nn * NHID; o += 256) {
            int n2 = o >> 7, c = o & 127;
            float acc = nb1l[c];
            const float* nir = s_ni + n2 * NIN;
            const float* w = nw1l + c;
            #pragma unroll 4
            for (int ig = 0; ig < 20; ++ig) {
                float4 f4 = *(const float4*)(nir + 4 * ig);
                acc = fmaf(f4.x, w[(4 * ig + 0) * NHID], acc);
                acc = fmaf(f4.y, w[(4 * ig + 1) * NHID], acc);
                acc = fmaf(f4.z, w[(4 * ig + 2) * NHID], acc);
                acc = fmaf(f4.w, w[(4 * ig + 3) * NHID], acc);
            }
            s_nh[n2 * NHID + c] = silu_f(acc);
        }
        __syncthreads();

        // ---- node MLP out + residual: update s_f in place (owner lane) ----
        for (int o = tid; o < Nn * DIMq; o += 256) {
            int n2 = o >> 6, c = o & 63;
            float acc = nb2l[c];
            const float* nhr = s_nh + n2 * NHID;
            const float* w = nw2l + c;
            #pragma unroll 4
            for (int ig = 0; ig < 32; ++ig) {
                float4 f4 = *(const float4*)(nhr + 4 * ig);
                acc = fmaf(f4.x, w[(4 * ig + 0) * DIMq], acc);
                acc = fmaf(f4.y, w[(4 * ig + 1) * DIMq], acc);
                acc = fmaf(f4.z, w[(4 * ig + 2) * DIMq], acc);
                acc = fmaf(f4.w, w[(4 * ig + 3) * DIMq], acc);
            }
            s_f[n2][c] = acc + s_f[n2][c];
        }
        cp ^= 1;
    }
    __syncthreads();

    // ---- fused readout: mol mean -> silu(mol@rw1+rb1)@rw2 + rb2 ----
    float* s_mol = uPQ;
    if (tid < DIMq) {
        float acc = 0.f;
        for (int n = 0; n < Nn; ++n) acc += s_f[n][tid];
        s_mol[tid] = acc / 29.0f;
    }
    __syncthreads();
    if (tid < DIMq) {
        float a2 = rb1[tid];
        for (int i = 0; i < DIMq; ++i) a2 = fmaf(s_mol[i], rw1[i * DIMq + tid], a2);
        float part = silu_f(a2) * rw2[tid];
        #pragma unroll
        for (int off = 32; off > 0; off >>= 1) part += __shfl_down(part, off);
        if (tid == 0) out[b] = part + rb2[0];
    }
}

extern "C" void kernel_launch(void* const* d_in, const int* in_sizes, int n_in,
                              void* d_out, int out_size, void* d_ws, size_t ws_size,
                              hipStream_t stream) {
    const int*   tokens = (const int*)d_in[0];
    const float* coords = (const float*)d_in[1];
    // d_in[2] = mask : all-True in this problem
    const float* temb = (const float*)d_in[3];
    const float* pemb = (const float*)d_in[4];
    const float* ew1 = (const float*)d_in[5];
    const float* eb1 = (const float*)d_in[6];
    const float* ew2 = (const float*)d_in[7];
    const float* eb2 = (const float*)d_in[8];
    const float* cw1 = (const float*)d_in[9];
    const float* cb1 = (const float*)d_in[10];
    const float* cw2 = (const float*)d_in[11];
    const float* cb2 = (const float*)d_in[12];
    const float* csc = (const float*)d_in[13];
    const float* lng = (const float*)d_in[14];
    const float* lnb = (const float*)d_in[15];
    const float* nw1 = (const float*)d_in[16];
    const float* nb1 = (const float*)d_in[17];
    const float* nw2 = (const float*)d_in[18];
    const float* nb2 = (const float*)d_in[19];
    const float* rw1 = (const float*)d_in[20];
    const float* rb1 = (const float*)d_in[21];
    const float* rw2 = (const float*)d_in[22];
    const float* rb2 = (const float*)d_in[23];

    k_egnn<<<Bq, 256, 0, stream>>>(tokens, coords, temb, pemb,
                                   ew1, eb1, ew2, eb2,
                                   cw1, cb1, cw2, cb2, csc,
                                   lng, lnb, nw1, nb1, nw2, nb2,
                                   rw1, rb1, rw2, rb2, (float*)d_out);
}

// Round 15
// 616.794 us; speedup vs baseline: 1.3250x; 1.3250x over previous
//
#include <hip/hip_runtime.h>
#include <math.h>

#define Bq    1024
#define Nn    29
#define DIMq  64
#define Kq    8
#define MD    16
#define EIN   129
#define EH    258   // 2*EIN
#define CHID  64    // 4*MD
#define NIN   80    // DIM+MD
#define NHID  128   // 2*DIM
#define DEPTHq 4
#define NPASS 4
#define PQS   68    // P/Q LDS row stride (64+4)
#define FS    68    // s_f row stride
#define UPQN  6032  // max(2*29*68=3944, ni 2320 + nh 3712 = 6032)

__device__ __forceinline__ float silu_f(float x) {
    float e = __expf(-x);
    return x * __builtin_amdgcn_rcpf(1.0f + e);
}

// BEST KNOWN (R8, 616us): whole-network fusion, one block = one molecule
// through init + 4 EGNN layers + readout; feats/coors LDS-resident across
// layers. launch_bounds(256,4) — (512,8)[R6] and (256,5)[R11] force VGPR
// steps the allocator can't hit -> catastrophic scratch spill. Packed f32x2
// math regressed 3x (R10/R14: compiler scalarizes with pack overhead).
// Occupancy is GRID-capped at 4 blocks/CU (1024 blocks / 256 CU).
__global__ __launch_bounds__(256, 4)
void k_egnn(const int* __restrict__ tokens, const float* __restrict__ coords,
            const float* __restrict__ temb, const float* __restrict__ pemb,
            const float* __restrict__ ew1, const float* __restrict__ eb1,
            const float* __restrict__ ew2, const float* __restrict__ eb2,
            const float* __restrict__ cw1, const float* __restrict__ cb1,
            const float* __restrict__ cw2, const float* __restrict__ cb2,
            const float* __restrict__ csc,
            const float* __restrict__ lng, const float* __restrict__ lnb,
            const float* __restrict__ nw1, const float* __restrict__ nb1,
            const float* __restrict__ nw2, const float* __restrict__ nb2,
            const float* __restrict__ rw1, const float* __restrict__ rb1,
            const float* __restrict__ rw2, const float* __restrict__ rb2,
            float* __restrict__ out) {
    __shared__ float uPQ[UPQN];            // P/Q panels per pass; later ni/nh; finally mol
    __shared__ float s_f[Nn][FS];          // persistent feats (updated in place per layer)
    __shared__ float s_c[2][Nn][3];        // coords, double-buffered per layer
    __shared__ int   s_idx[Nn][Kq];
    __shared__ float s_dk[Nn][Kq];
    __shared__ union RegB {                // d2 dead after kNN -> cw/mi
        float d2[Nn][Nn];
        struct { float cw[232]; float mi[Nn][MD]; } e;
    } ub;
    float* s_ni = uPQ;                     // [Nn][NIN]
    float* s_nh = uPQ + Nn * NIN;          // [Nn][NHID]

    const int b = blockIdx.x;
    const int tid = threadIdx.x;

    // ---- init: feats = token_emb[tokens] + pos_emb ; stage coords ----
    for (int o = tid; o < Nn * DIMq; o += 256) {
        int n = o >> 6, d = o & 63;
        s_f[n][d] = temb[tokens[b * Nn + n] * DIMq + d] + pemb[o];
    }
    if (tid < Nn * 3) s_c[0][0][tid] = coords[(size_t)b * Nn * 3 + tid];
    int cp = 0;

    for (int l = 0; l < DEPTHq; ++l) {
        const float* ew1l = ew1 + (size_t)l * EIN * EH;  const float* eb1l = eb1 + l * EH;
        const float* ew2l = ew2 + (size_t)l * EH * MD;   const float* eb2l = eb2 + l * MD;
        const float* cw1l = cw1 + (size_t)l * MD * CHID; const float* cb1l = cb1 + l * CHID;
        const float* cw2l = cw2 + l * CHID;              const float* cb2l = cb2 + l;
        const float* lngl = lng + l * DIMq;              const float* lnbl = lnb + l * DIMq;
        const float* nw1l = nw1 + (size_t)l * NIN * NHID;  const float* nb1l = nb1 + l * NHID;
        const float* nw2l = nw2 + (size_t)l * NHID * DIMq; const float* nb2l = nb2 + l * DIMq;
        const float cscale = csc[l];

        __syncthreads();   // s_f/s_c/uPQ stable before this layer reads them

        // ---- all-pairs squared distances (exact rounding: kNN-critical) ----
        for (int o = tid; o < Nn * Nn; o += 256) {
            int i = o / Nn, j = o % Nn;
            float dx = __fsub_rn(s_c[cp][i][0], s_c[cp][j][0]);
            float dy = __fsub_rn(s_c[cp][i][1], s_c[cp][j][1]);
            float dz = __fsub_rn(s_c[cp][i][2], s_c[cp][j][2]);
            ub.d2[i][j] = __fadd_rn(__fadd_rn(__fmul_rn(dx, dx), __fmul_rn(dy, dy)),
                                    __fmul_rn(dz, dz));
        }
        __syncthreads();

        // ---- parallel stable K-nearest: 8 lanes per node (tie: dist2, then index) ----
        if (tid < Nn * Kq) {
            const int g = tid >> 3, lk = tid & 7;
            unsigned chosen = 0;
            for (int r = 0; r < Kq; ++r) {
                float bv = 3.4e38f; int bj = 64;
                for (int j = lk; j < Nn; j += 8) {
                    if ((chosen >> j) & 1u) continue;
                    float v = ub.d2[g][j];
                    if (v < bv) { bv = v; bj = j; }
                }
                #pragma unroll
                for (int off = 1; off < 8; off <<= 1) {
                    float ov = __shfl_xor(bv, off);
                    int   oj = __shfl_xor(bj, off);
                    if (ov < bv || (ov == bv && oj < bj)) { bv = ov; bj = oj; }
                }
                chosen |= 1u << bj;
                if (lk == 0) { s_idx[g][r] = bj; s_dk[g][r] = bv; }
            }
        }
        __syncthreads();

        // ---- edge state (uniform flow; writes masked) ----
        const int e   = (tid < 232) ? tid : 231;
        const int n_e = e >> 3;
        const int k_e = e & 7;
        const int jj  = s_idx[n_e][k_e];
        const float dd = s_dk[n_e][k_e];
        float m[MD];
        #pragma unroll
        for (int q = 0; q < MD; ++q) m[q] = 0.f;

#define ACC_COL(Pv, Qv, CG) do {                                  \
        float pre = (Pv) + (Qv) + dd * wdrow[CG];                 \
        float h = silu_f(pre);                                    \
        const float* w2r = ew2l + (size_t)(CG) * MD;              \
        _Pragma("unroll")                                         \
        for (int q = 0; q < MD; ++q) m[q] = fmaf(h, w2r[q], m[q]);\
    } while (0)

        // ---- four c-passes (64,64,64,66 cols): P/Q panels -> edge accumulation ----
        for (int pass = 0; pass < NPASS; ++pass) {
            const int c0 = pass * 64;
            const int cols = (pass == 3) ? 66 : 64;

            // P/Q: 4*cols tasks = cols x {P,Q} x {rows 0-14, 15-28}; 256 tasks/pass
            for (int it = 0; it < 2; ++it) {
                const int t = tid + it * 256;
                if (t >= 4 * cols) break;
                const int cl = t >> 2, r = t & 3;
                const bool isP = r < 2;
                const bool full15 = (r & 1) == 0;
                const int n0 = (r & 1) * 15;
                const int cg = c0 + cl;
                const float* wcol = ew1l + (isP ? 0 : 64) * EH + cg;
                float init = isP ? eb1l[cg] : 0.f;
                float acc[15];
                #pragma unroll
                for (int u = 0; u < 15; ++u) acc[u] = init;
                #pragma unroll 2
                for (int ig = 0; ig < 16; ++ig) {
                    float w0 = wcol[(4 * ig + 0) * EH], w1 = wcol[(4 * ig + 1) * EH];
                    float w2v = wcol[(4 * ig + 2) * EH], w3 = wcol[(4 * ig + 3) * EH];
                    #pragma unroll
                    for (int u = 0; u < 14; ++u) {
                        float4 f4 = *(const float4*)&s_f[n0 + u][4 * ig];
                        acc[u] = fmaf(f4.x, w0, acc[u]);
                        acc[u] = fmaf(f4.y, w1, acc[u]);
                        acc[u] = fmaf(f4.z, w2v, acc[u]);
                        acc[u] = fmaf(f4.w, w3, acc[u]);
                    }
                    if (full15) {
                        float4 f4 = *(const float4*)&s_f[14][4 * ig];
                        acc[14] = fmaf(f4.x, w0, acc[14]);
                        acc[14] = fmaf(f4.y, w1, acc[14]);
                        acc[14] = fmaf(f4.z, w2v, acc[14]);
                        acc[14] = fmaf(f4.w, w3, acc[14]);
                    }
                }
                const int rbase = (isP ? 0 : Nn) + n0;
                #pragma unroll
                for (int u = 0; u < 14; ++u) uPQ[(rbase + u) * PQS + cl] = acc[u];
                if (full15) uPQ[(rbase + 14) * PQS + cl] = acc[14];
            }
            __syncthreads();

            // edge accumulation over this pass (uniform loop; scalar weight reads)
            {
                const float* Prow = uPQ + n_e * PQS;
                const float* Qrow = uPQ + (Nn + jj) * PQS;
                const float* wdrow = ew1l + 128 * EH;
                for (int qd = 0; qd < 16; ++qd) {
                    const int cl = 4 * qd;
                    float4 P4 = *(const float4*)(Prow + cl);
                    float4 Q4 = *(const float4*)(Qrow + cl);
                    const int cg = c0 + cl;
                    ACC_COL(P4.x, Q4.x, cg);
                    ACC_COL(P4.y, Q4.y, cg + 1);
                    ACC_COL(P4.z, Q4.z, cg + 2);
                    ACC_COL(P4.w, Q4.w, cg + 3);
                }
                if (pass == 3) {
                    ACC_COL(Prow[64], Qrow[64], c0 + 64);
                    ACC_COL(Prow[65], Qrow[65], c0 + 65);
                }
            }
            __syncthreads();
        }
#undef ACC_COL

        // ---- finish edge: m silu, coor MLP, cw + mi pool ----
        {
            #pragma unroll
            for (int q = 0; q < MD; ++q) m[q] = silu_f(eb2l[q] + m[q]);

            float cwacc = cb2l[0];
            #pragma unroll
            for (int ch = 0; ch < 4; ++ch) {
                float hh[16];
                const float* cb1c = cb1l + 16 * ch;
                #pragma unroll
                for (int q = 0; q < 16; ++q) hh[q] = cb1c[q];
                #pragma unroll
                for (int i = 0; i < MD; ++i) {
                    const float* wr = cw1l + i * CHID + 16 * ch;   // uniform -> s_load
                    #pragma unroll
                    for (int q = 0; q < 16; ++q) hh[q] = fmaf(m[i], wr[q], hh[q]);
                }
                const float* cw2c = cw2l + 16 * ch;
                #pragma unroll
                for (int q = 0; q < 16; ++q) cwacc = fmaf(silu_f(hh[q]), cw2c[q], cwacc);
            }
            cwacc = fminf(fmaxf(cwacc, -2.f), 2.f);
            if (tid < 232) ub.e.cw[e] = cwacc;

            #pragma unroll
            for (int q = 0; q < MD; ++q) {
                float v = m[q];
                v += __shfl_xor(v, 1);
                v += __shfl_xor(v, 2);
                v += __shfl_xor(v, 4);
                if (k_e == 0 && tid < 232) ub.e.mi[n_e][q] = v;
            }
        }
        __syncthreads();

        // ---- coords update (87 lanes -> s_c[cp^1]) + LayerNorm/ni build (232 lanes) ----
        if (tid < Nn * 3) {
            int n2 = tid / 3, cix = tid % 3;
            float acc2 = 0.f;
            for (int k2 = 0; k2 < Kq; ++k2) {
                int j2 = s_idx[n2][k2];
                float nrm = sqrtf(s_dk[n2][k2]);
                float rel = __fsub_rn(s_c[cp][n2][cix], s_c[cp][j2][cix]);
                float rn = rel / fmaxf(nrm, 1e-8f) * cscale;
                acc2 = fmaf(ub.e.cw[n2 * Kq + k2], rn, acc2);
            }
            s_c[cp ^ 1][n2][cix] = s_c[cp][n2][cix] + acc2;   // write other buffer: no race
        }
        if (tid < Nn * Kq) {
            const int g = tid >> 3, lk = tid & 7;
            const float* fr = s_f[g];
            float4 a = *(const float4*)&fr[8 * lk];
            float4 b4 = *(const float4*)&fr[8 * lk + 4];
            float ps = ((a.x + a.y) + (a.z + a.w)) + ((b4.x + b4.y) + (b4.z + b4.w));
            ps += __shfl_xor(ps, 1); ps += __shfl_xor(ps, 2); ps += __shfl_xor(ps, 4);
            float mu = ps * (1.0f / 64.0f);
            float t0, pv = 0.f;
            t0 = a.x - mu;  pv = fmaf(t0, t0, pv);  t0 = a.y - mu;  pv = fmaf(t0, t0, pv);
            t0 = a.z - mu;  pv = fmaf(t0, t0, pv);  t0 = a.w - mu;  pv = fmaf(t0, t0, pv);
            t0 = b4.x - mu; pv = fmaf(t0, t0, pv);  t0 = b4.y - mu; pv = fmaf(t0, t0, pv);
            t0 = b4.z - mu; pv = fmaf(t0, t0, pv);  t0 = b4.w - mu; pv = fmaf(t0, t0, pv);
            pv += __shfl_xor(pv, 1); pv += __shfl_xor(pv, 2); pv += __shfl_xor(pv, 4);
            float rs = rsqrtf(pv * (1.0f / 64.0f) + 1e-5f);
            #pragma unroll
            for (int u = 0; u < 8; ++u) {
                int d = 8 * lk + u;
                s_ni[g * NIN + d] = (fr[d] - mu) * rs * lngl[d] + lnbl[d];
            }
            if (lk < 2) {
                #pragma unroll
                for (int u = 0; u < 8; ++u)
                    s_ni[g * NIN + DIMq + 8 * lk + u] = ub.e.mi[g][8 * lk + u];
            }
        }
        __syncthreads();

        // ---- node MLP hidden ----
        for (int o = tid; o < Nn * NHID; o += 256) {
            int n2 = o >> 7, c = o & 127;
            float acc = nb1l[c];
            const float* nir = s_ni + n2 * NIN;
            const float* w = nw1l + c;
            #pragma unroll 4
            for (int ig = 0; ig < 20; ++ig) {
                float4 f4 = *(const float4*)(nir + 4 * ig);
                acc = fmaf(f4.x, w[(4 * ig + 0) * NHID], acc);
                acc = fmaf(f4.y, w[(4 * ig + 1) * NHID], acc);
                acc = fmaf(f4.z, w[(4 * ig + 2) * NHID], acc);
                acc = fmaf(f4.w, w[(4 * ig + 3) * NHID], acc);
            }
            s_nh[n2 * NHID + c] = silu_f(acc);
        }
        __syncthreads();

        // ---- node MLP out + residual: update s_f in place (owner lane) ----
        for (int o = tid; o < Nn * DIMq; o += 256) {
            int n2 = o >> 6, c = o & 63;
            float acc = nb2l[c];
            const float* nhr = s_nh + n2 * NHID;
            const float* w = nw2l + c;
            #pragma unroll 4
            for (int ig = 0; ig < 32; ++ig) {
                float4 f4 = *(const float4*)(nhr + 4 * ig);
                acc = fmaf(f4.x, w[(4 * ig + 0) * DIMq], acc);
                acc = fmaf(f4.y, w[(4 * ig + 1) * DIMq], acc);
                acc = fmaf(f4.z, w[(4 * ig + 2) * DIMq], acc);
                acc = fmaf(f4.w, w[(4 * ig + 3) * DIMq], acc);
            }
            s_f[n2][c] = acc + s_f[n2][c];
        }
        cp ^= 1;
    }
    __syncthreads();

    // ---- fused readout: mol mean -> silu(mol@rw1+rb1)@rw2 + rb2 ----
    float* s_mol = uPQ;
    if (tid < DIMq) {
        float acc = 0.f;
        for (int n = 0; n < Nn; ++n) acc += s_f[n][tid];
        s_mol[tid] = acc / 29.0f;
    }
    __syncthreads();
    if (tid < DIMq) {
        float a2 = rb1[tid];
        for (int i = 0; i < DIMq; ++i) a2 = fmaf(s_mol[i], rw1[i * DIMq + tid], a2);
        float part = silu_f(a2) * rw2[tid];
        #pragma unroll
        for (int off = 32; off > 0; off >>= 1) part += __shfl_down(part, off);
        if (tid == 0) out[b] = part + rb2[0];
    }
}

extern "C" void kernel_launch(void* const* d_in, const int* in_sizes, int n_in,
                              void* d_out, int out_size, void* d_ws, size_t ws_size,
                              hipStream_t stream) {
    const int*   tokens = (const int*)d_in[0];
    const float* coords = (const float*)d_in[1];
    // d_in[2] = mask : all-True in this problem
    const float* temb = (const float*)d_in[3];
    const float* pemb = (const float*)d_in[4];
    const float* ew1 = (const float*)d_in[5];
    const float* eb1 = (const float*)d_in[6];
    const float* ew2 = (const float*)d_in[7];
    const float* eb2 = (const float*)d_in[8];
    const float* cw1 = (const float*)d_in[9];
    const float* cb1 = (const float*)d_in[10];
    const float* cw2 = (const float*)d_in[11];
    const float* cb2 = (const float*)d_in[12];
    const float* csc = (const float*)d_in[13];
    const float* lng = (const float*)d_in[14];
    const float* lnb = (const float*)d_in[15];
    const float* nw1 = (const float*)d_in[16];
    const float* nb1 = (const float*)d_in[17];
    const float* nw2 = (const float*)d_in[18];
    const float* nb2 = (const float*)d_in[19];
    const float* rw1 = (const float*)d_in[20];
    const float* rb1 = (const float*)d_in[21];
    const float* rw2 = (const float*)d_in[22];
    const float* rb2 = (const float*)d_in[23];

    k_egnn<<<Bq, 256, 0, stream>>>(tokens, coords, temb, pemb,
                                   ew1, eb1, ew2, eb2,
                                   cw1, cb1, cw2, cb2, csc,
                                   lng, lnb, nw1, nb1, nw2, nb2,
                                   rw1, rb1, rw2, rb2, (float*)d_out);
}